// Round 6
// baseline (104.836 us; speedup 1.0000x reference)
//
#include <hip/hip_runtime.h>

#define BATCH  8
#define CH     64
#define H      128
#define W      128
#define HW     (H * W)             // 16384
#define RS     4                   // rows per wave strip
#define CPW    4                   // channels per wave
#define NCHUNK (CH / CPW)          // 16 partial planes
#define NSTRIP (H / RS)            // 32

typedef float        vfloat2 __attribute__((ext_vector_type(2)));
typedef float        vfloat4 __attribute__((ext_vector_type(4)));
typedef unsigned int uint;
typedef uint         vuint2  __attribute__((ext_vector_type(2)));

// sigmoid via v_rcp + one Newton step (absmax 0.0 verified in this config).
// Exponent arg clamped so e stays finite; for x <= -80 returns ~1.8e-35.
__device__ __forceinline__ float sigmoidf_(float v) {
    float e = __expf(fminf(-v, 80.0f));
    float d = 1.0f + e;
    float r = __builtin_amdgcn_rcpf(d);
    r = r * __builtin_fmaf(-d, r, 2.0f);   // one NR refinement
    return r;
}

// wave-uniform value -> SGPR (VALU reads the SGPR operand for free)
__device__ __forceinline__ float uniformf_(float v) {
    return __int_as_float(__builtin_amdgcn_readfirstlane(__float_as_int(v)));
}

// pack two f32 -> two bf16 (RNE) in one u32:  lo = a, hi = b
__device__ __forceinline__ uint pack_bf16_(float a, float b) {
    uint ua = __float_as_uint(a);
    uint ub = __float_as_uint(b);
    ua = (ua + 0x7FFFu + ((ua >> 16) & 1u)) >> 16;
    ub = (ub + 0x7FFFu + ((ub >> 16) & 1u)) & 0xFFFF0000u;
    return ua | ub;
}

// D_k = max(wk,p_k)+bk over the 3x3 window (row-major p0..p8, center p4).
// sum association identical to the verified baseline (absmax 0.0).
// Exact median-of-9 in 13 VOP3 ops: partition into the 3 columns,
// med9 = med3( max3(col mins), med3(col meds), min3(col maxs) ).
__device__ __forceinline__ float pixel_val(
    const float p0, const float p1, const float p2,
    const float p3, const float p4, const float p5,
    const float p6, const float p7, const float p8,
    const float* __restrict__ wk, const float* __restrict__ bk,
    const float wc, const float wm)
{
    float d0 = fmaxf(wk[0], p0) + bk[0];
    float d1 = fmaxf(wk[1], p1) + bk[1];
    float d2 = fmaxf(wk[2], p2) + bk[2];
    float d3 = fmaxf(wk[3], p3) + bk[3];
    float d4 = fmaxf(wk[4], p4) + bk[4];
    float d5 = fmaxf(wk[5], p5) + bk[5];
    float d6 = fmaxf(wk[6], p6) + bk[6];
    float d7 = fmaxf(wk[7], p7) + bk[7];
    float d8 = fmaxf(wk[8], p8) + bk[8];

    float sum = ((d0 + d1) + (d2 + d3)) + ((d5 + d6) + (d7 + d8)) + d4;

    float mn0 = fminf(fminf(d0, d3), d6);              // -> v_min3
    float md0 = __builtin_amdgcn_fmed3f(d0, d3, d6);   // -> v_med3
    float mx0 = fmaxf(fmaxf(d0, d3), d6);              // -> v_max3
    float mn1 = fminf(fminf(d1, d4), d7);
    float md1 = __builtin_amdgcn_fmed3f(d1, d4, d7);
    float mx1 = fmaxf(fmaxf(d1, d4), d7);
    float mn2 = fminf(fminf(d2, d5), d8);
    float md2 = __builtin_amdgcn_fmed3f(d2, d5, d8);
    float mx2 = fmaxf(fmaxf(d2, d5), d8);

    float lo  = fmaxf(fmaxf(mn0, mn1), mn2);
    float mid = __builtin_amdgcn_fmed3f(md0, md1, md2);
    float hi  = fminf(fminf(mx0, mx1), mx2);
    float med = __builtin_amdgcn_fmed3f(lo, mid, hi);

    return wc * p4 + wm * med - sum - sum * (1.0f / 9.0f);
}

// Kernel 1: wave-autonomous register stencil, NO barriers, NO atomics.
// Lane l owns columns [2l, 2l+2); a wave sweeps a 4-row strip x 4 channels.
// 1024 blocks -> 4 blocks/CU, 4 waves/SIMD. All 24 row-loads batch-issued
// into registers, then sigmoid + shfl + median run out of registers.
// The 4-channel partial is stored as bf16(RNE) into ws[b][chunk][h][w] --
// halving the ws HBM round-trip vs f32.
__global__ __launch_bounds__(256) void partial_kernel(
    const float* __restrict__ x,
    const float* __restrict__ weight,
    const float* __restrict__ bias,
    const float* __restrict__ wcp,
    const float* __restrict__ wmp,
    unsigned short* __restrict__ ws)
{
    const int tid   = threadIdx.x;
    const int lane  = tid & 63;
    const int strip = blockIdx.x * 4 + (tid >> 6);   // 0..31
    const int chnk  = blockIdx.y;                    // 0..15
    const int c0    = chnk * CPW;
    const int b     = blockIdx.z;

    const int row0 = strip * RS;
    const int col  = 2 * lane;

    // weights/biases are wave-uniform -> keep them in SGPRs
    float wk[9], bk[9];
    #pragma unroll
    for (int k = 0; k < 9; ++k) {
        wk[k] = uniformf_(sigmoidf_(weight[k]));
        bk[k] = uniformf_(sigmoidf_(bias[k]));
    }
    const float wc = uniformf_(wcp[0]);
    const float wm = uniformf_(wmp[0]);

    // ---- batch-issue ALL row loads first (independent addresses) ----
    vfloat2 raw[CPW][RS + 2];
    #pragma unroll
    for (int cc = 0; cc < CPW; ++cc) {
        const float* base = x + ((size_t)b * CH + c0 + cc) * HW + col;
        #pragma unroll
        for (int rr = 0; rr < RS + 2; ++rr) {
            const int r_  = row0 + rr - 1;
            const int rcl = min(max(r_, 0), H - 1);
            raw[cc][rr] = *(const vfloat2*)(base + rcl * W);
        }
    }

    vfloat2 acc[RS];
    #pragma unroll
    for (int j = 0; j < RS; ++j) acc[j] = (vfloat2)(0.0f);

    // sigmoid + pad + horizontal halo for one staged row
    #define SIGROW(cc, rr, Lr, Ar, Br, Rr)                                    \
    {                                                                         \
        const int  r_  = row0 + (rr) - 1;                                     \
        const bool okr = (r_ >= 0) & (r_ < H);                                \
        vfloat2 v = raw[cc][rr];                                              \
        Ar = okr ? sigmoidf_(v.x) : 0.0f;                                     \
        Br = okr ? sigmoidf_(v.y) : 0.0f;                                     \
        float lf = __shfl_up(Br, 1);                                          \
        float rg = __shfl_down(Ar, 1);                                        \
        Lr = (lane == 0)  ? 0.0f : lf;                                        \
        Rr = (lane == 63) ? 0.0f : rg;                                        \
    }

    #pragma unroll
    for (int cc = 0; cc < CPW; ++cc) {
        float L0, A0, B0, R0, L1, A1, B1, R1, L2, A2, B2, R2;
        SIGROW(cc, 0, L0, A0, B0, R0);
        SIGROW(cc, 1, L1, A1, B1, R1);

        #pragma unroll
        for (int j = 0; j < RS; ++j) {
            SIGROW(cc, j + 2, L2, A2, B2, R2);

            acc[j].x += pixel_val(L0, A0, B0,
                                  L1, A1, B1,
                                  L2, A2, B2, wk, bk, wc, wm);
            acc[j].y += pixel_val(A0, B0, R0,
                                  A1, B1, R1,
                                  A2, B2, R2, wk, bk, wc, wm);

            L0 = L1; A0 = A1; B0 = B1; R0 = R1;
            L1 = L2; A1 = A2; B1 = B2; R1 = R2;
        }
    }
    #undef SIGROW

    // exclusive partial-plane store: 2 bf16 per lane-row (dword, coalesced)
    unsigned short* op = ws + ((size_t)b * NCHUNK + chnk) * HW
                            + (size_t)row0 * W + col;
    #pragma unroll
    for (int j = 0; j < RS; ++j)
        *(uint*)(op + (size_t)j * W) = pack_bf16_(acc[j].x, acc[j].y);
}

// Kernel 2: per pixel, sum the 16 bf16 partial planes (L2/L3-hot, 4 MB),
// broadcast to 32 of the 64 output planes per blockIdx.y group (256 blocks
// = 1/CU). dwordx4 nontemporal stores keep the out-stream out of L2.
__global__ __launch_bounds__(256) void broadcast_kernel(
    const unsigned short* __restrict__ ws,
    float* __restrict__ out)
{
    const int g  = (blockIdx.x * 256 + threadIdx.x) * 4;   // pixel base
    const int b  = g >> 14;                                 // HW = 16384
    const int p  = g & (HW - 1);
    const int c0 = blockIdx.y * 32;

    const unsigned short* wsb = ws + (size_t)b * NCHUNK * HW + p;
    vfloat4 s = (vfloat4)(0.0f);
    #pragma unroll
    for (int k = 0; k < NCHUNK; ++k) {
        vuint2 v = *(const vuint2*)(wsb + (size_t)k * HW);   // 4 bf16
        s.x += __uint_as_float(v.x << 16);
        s.y += __uint_as_float(v.x & 0xFFFF0000u);
        s.z += __uint_as_float(v.y << 16);
        s.w += __uint_as_float(v.y & 0xFFFF0000u);
    }

    float* base = out + ((size_t)b * CH + c0) * HW + p;
    #pragma unroll
    for (int j = 0; j < 32; ++j)
        __builtin_nontemporal_store(s, (vfloat4*)(base + (size_t)j * HW));
}

extern "C" void kernel_launch(void* const* d_in, const int* in_sizes, int n_in,
                              void* d_out, int out_size, void* d_ws, size_t ws_size,
                              hipStream_t stream) {
    const float* x      = (const float*)d_in[0];
    const float* weight = (const float*)d_in[1];
    const float* bias   = (const float*)d_in[2];
    const float* wcp    = (const float*)d_in[3];
    const float* wmp    = (const float*)d_in[4];
    float* out = (float*)d_out;
    unsigned short* ws = (unsigned short*)d_ws;   // 8*16*16384*2 B = 4 MiB

    dim3 grid1(NSTRIP / 4, NCHUNK, BATCH);        // 8 x 16 x 8 = 1024 blocks
    partial_kernel<<<grid1, 256, 0, stream>>>(x, weight, bias, wcp, wmp, ws);

    dim3 grid2(BATCH * HW / (4 * 256), CH / 32);  // 128 x 2 = 256 blocks
    broadcast_kernel<<<grid2, 256, 0, stream>>>(ws, out);
}

// Round 7
// 102.269 us; speedup vs baseline: 1.0251x; 1.0251x over previous
//
#include <hip/hip_runtime.h>

#define BATCH  8
#define CH     64
#define H      128
#define W      128
#define HW     (H * W)             // 16384
#define RS     4                   // rows per wave strip
#define CPW    4                   // channels per wave
#define NCHUNK (CH / CPW)          // 16 partial planes
#define NSTRIP (H / RS)            // 32

typedef float vfloat2 __attribute__((ext_vector_type(2)));
typedef float vfloat4 __attribute__((ext_vector_type(4)));

// sigmoid via raw v_rcp (~2^-22 rel err, well inside harness tolerance).
// Exponent arg clamped so e stays finite; for x <= -80 returns ~1.8e-35.
__device__ __forceinline__ float sigmoidf_(float v) {
    float e = __expf(fminf(-v, 80.0f));
    return __builtin_amdgcn_rcpf(1.0f + e);
}

// wave-uniform value -> SGPR (VALU reads the SGPR operand for free)
__device__ __forceinline__ float uniformf_(float v) {
    return __int_as_float(__builtin_amdgcn_readfirstlane(__float_as_int(v)));
}

// D_k = max(wk,p_k)+bk over the 3x3 window (row-major p0..p8, center p4).
// Exact median-of-9 in 13 VOP3 ops: partition into the 3 columns,
// med9 = med3( max3(col mins), med3(col meds), min3(col maxs) ).
// -sum - sum/9 folded to fma(sum, -10/9, .).
__device__ __forceinline__ float pixel_val(
    const float p0, const float p1, const float p2,
    const float p3, const float p4, const float p5,
    const float p6, const float p7, const float p8,
    const float* __restrict__ wk, const float* __restrict__ bk,
    const float wc, const float wm)
{
    float d0 = fmaxf(wk[0], p0) + bk[0];
    float d1 = fmaxf(wk[1], p1) + bk[1];
    float d2 = fmaxf(wk[2], p2) + bk[2];
    float d3 = fmaxf(wk[3], p3) + bk[3];
    float d4 = fmaxf(wk[4], p4) + bk[4];
    float d5 = fmaxf(wk[5], p5) + bk[5];
    float d6 = fmaxf(wk[6], p6) + bk[6];
    float d7 = fmaxf(wk[7], p7) + bk[7];
    float d8 = fmaxf(wk[8], p8) + bk[8];

    float sum = ((d0 + d1) + (d2 + d3)) + ((d5 + d6) + (d7 + d8)) + d4;

    float mn0 = fminf(fminf(d0, d3), d6);              // -> v_min3
    float md0 = __builtin_amdgcn_fmed3f(d0, d3, d6);   // -> v_med3
    float mx0 = fmaxf(fmaxf(d0, d3), d6);              // -> v_max3
    float mn1 = fminf(fminf(d1, d4), d7);
    float md1 = __builtin_amdgcn_fmed3f(d1, d4, d7);
    float mx1 = fmaxf(fmaxf(d1, d4), d7);
    float mn2 = fminf(fminf(d2, d5), d8);
    float md2 = __builtin_amdgcn_fmed3f(d2, d5, d8);
    float mx2 = fmaxf(fmaxf(d2, d5), d8);

    float lo  = fmaxf(fmaxf(mn0, mn1), mn2);
    float mid = __builtin_amdgcn_fmed3f(md0, md1, md2);
    float hi  = fminf(fminf(mx0, mx1), mx2);
    float med = __builtin_amdgcn_fmed3f(lo, mid, hi);

    return __builtin_fmaf(sum, -10.0f / 9.0f,
                          __builtin_fmaf(wm, med, wc * p4));
}

// Kernel 1: wave-autonomous register stencil, NO barriers, NO atomics.
// Lane l owns columns [2l, 2l+2); a wave sweeps a 4-row strip x 4 channels.
// 1024 blocks -> 4 blocks/CU, 4 waves/SIMD (the RS=8/CPW=4 variant halved
// this and regressed). All 24 row-loads are batch-issued into registers,
// then sigmoid + shfl + median run out of registers. The 4-channel partial
// is stored exclusively into ws[b][chunk][h][w].
__global__ __launch_bounds__(256) void partial_kernel(
    const float* __restrict__ x,
    const float* __restrict__ weight,
    const float* __restrict__ bias,
    const float* __restrict__ wcp,
    const float* __restrict__ wmp,
    float* __restrict__ ws)
{
    const int tid   = threadIdx.x;
    const int lane  = tid & 63;
    const int strip = blockIdx.x * 4 + (tid >> 6);   // 0..31
    const int chnk  = blockIdx.y;                    // 0..15
    const int c0    = chnk * CPW;
    const int b     = blockIdx.z;

    const int row0 = strip * RS;
    const int col  = 2 * lane;

    // weights/biases are wave-uniform -> keep them in SGPRs
    float wk[9], bk[9];
    #pragma unroll
    for (int k = 0; k < 9; ++k) {
        wk[k] = uniformf_(sigmoidf_(weight[k]));
        bk[k] = uniformf_(sigmoidf_(bias[k]));
    }
    const float wc = uniformf_(wcp[0]);
    const float wm = uniformf_(wmp[0]);

    // ---- batch-issue ALL row loads first (independent addresses) ----
    vfloat2 raw[CPW][RS + 2];
    #pragma unroll
    for (int cc = 0; cc < CPW; ++cc) {
        const float* base = x + ((size_t)b * CH + c0 + cc) * HW + col;
        #pragma unroll
        for (int rr = 0; rr < RS + 2; ++rr) {
            const int r_  = row0 + rr - 1;
            const int rcl = min(max(r_, 0), H - 1);
            raw[cc][rr] = *(const vfloat2*)(base + rcl * W);
        }
    }

    vfloat2 acc[RS];
    #pragma unroll
    for (int j = 0; j < RS; ++j) acc[j] = (vfloat2)(0.0f);

    // sigmoid + pad + horizontal halo for one staged row
    #define SIGROW(cc, rr, Lr, Ar, Br, Rr)                                    \
    {                                                                         \
        const int  r_  = row0 + (rr) - 1;                                     \
        const bool okr = (r_ >= 0) & (r_ < H);                                \
        vfloat2 v = raw[cc][rr];                                              \
        Ar = okr ? sigmoidf_(v.x) : 0.0f;                                     \
        Br = okr ? sigmoidf_(v.y) : 0.0f;                                     \
        float lf = __shfl_up(Br, 1);                                          \
        float rg = __shfl_down(Ar, 1);                                        \
        Lr = (lane == 0)  ? 0.0f : lf;                                        \
        Rr = (lane == 63) ? 0.0f : rg;                                        \
    }

    #pragma unroll
    for (int cc = 0; cc < CPW; ++cc) {
        float L0, A0, B0, R0, L1, A1, B1, R1, L2, A2, B2, R2;
        SIGROW(cc, 0, L0, A0, B0, R0);
        SIGROW(cc, 1, L1, A1, B1, R1);

        #pragma unroll
        for (int j = 0; j < RS; ++j) {
            SIGROW(cc, j + 2, L2, A2, B2, R2);

            acc[j].x += pixel_val(L0, A0, B0,
                                  L1, A1, B1,
                                  L2, A2, B2, wk, bk, wc, wm);
            acc[j].y += pixel_val(A0, B0, R0,
                                  A1, B1, R1,
                                  A2, B2, R2, wk, bk, wc, wm);

            L0 = L1; A0 = A1; B0 = B1; R0 = R1;
            L1 = L2; A1 = A2; B1 = B2; R1 = R2;
        }
    }
    #undef SIGROW

    // exclusive partial-plane store (fire-and-forget dwordx2)
    float* op = ws + ((size_t)b * NCHUNK + chnk) * HW + (size_t)row0 * W + col;
    #pragma unroll
    for (int j = 0; j < RS; ++j)
        *(vfloat2*)(op + (size_t)j * W) = acc[j];
}

// Kernel 2: per pixel, sum the 16 partial planes once, broadcast to 32 of
// the 64 output planes per blockIdx.y group (2 groups -> ws is re-read 2x
// instead of 4x; 256 blocks = exactly 1/CU so every CU carries writes).
// dwordx4 nontemporal stores keep the 33.5 MB out-stream out of L2.
__global__ __launch_bounds__(256) void broadcast_kernel(
    const float* __restrict__ ws,
    float* __restrict__ out)
{
    const int g  = (blockIdx.x * 256 + threadIdx.x) * 4;   // pixel base
    const int b  = g >> 14;                                 // HW = 16384
    const int p  = g & (HW - 1);
    const int c0 = blockIdx.y * 32;

    const float* wsb = ws + (size_t)b * NCHUNK * HW + p;
    vfloat4 s = (vfloat4)(0.0f);
    #pragma unroll
    for (int k = 0; k < NCHUNK; ++k)
        s += *(const vfloat4*)(wsb + (size_t)k * HW);

    float* base = out + ((size_t)b * CH + c0) * HW + p;
    #pragma unroll
    for (int j = 0; j < 32; ++j)
        __builtin_nontemporal_store(s, (vfloat4*)(base + (size_t)j * HW));
}

extern "C" void kernel_launch(void* const* d_in, const int* in_sizes, int n_in,
                              void* d_out, int out_size, void* d_ws, size_t ws_size,
                              hipStream_t stream) {
    const float* x      = (const float*)d_in[0];
    const float* weight = (const float*)d_in[1];
    const float* bias   = (const float*)d_in[2];
    const float* wcp    = (const float*)d_in[3];
    const float* wmp    = (const float*)d_in[4];
    float* out = (float*)d_out;
    float* ws  = (float*)d_ws;                    // 8*16*16384*4 B = 8 MiB

    dim3 grid1(NSTRIP / 4, NCHUNK, BATCH);        // 8 x 16 x 8 = 1024 blocks
    partial_kernel<<<grid1, 256, 0, stream>>>(x, weight, bias, wcp, wmp, ws);

    dim3 grid2(BATCH * HW / (4 * 256), CH / 32);  // 128 x 2 = 256 blocks
    broadcast_kernel<<<grid2, 256, 0, stream>>>(ws, out);
}